// Round 15
// baseline (416.284 us; speedup 1.0000x reference)
//
#include <hip/hip_runtime.h>
#include <hip/hip_bf16.h>

// TensorTrainLMN: out[b, a*128+h] = X[b,:] @ W[:, a*128+h] + bias
//   X[b] = [nh[b,0,:128], ..., nh[b,15,:128], te[b,:128]]   (K = 2176)
//
// tt_prep (72 blocks x 512): fold W -> Bp bricks [nb4][kt34][slot8][128][8]
//   bf16 + bias. (verified r13/r14)
// tt_gemm (FUSED single-pass, r14's 8-phase ledger + in-loop A cvt):
//   256x256xBK64, 512 thr (8 waves 2x4, wave 128x64), 128 KB LDS.
//   B: global_load_lds DMA of pre-packed bricks (r14 path, verified).
//   A: nh/te f32 reg-staged (32 f32/thread, va0/va1 named dbuf, loads issued
//   phases 2/6, cvt+ds_write 4-6 phases later; compiler-counted waits).
//   vmem FIFO per half-pair = [SB2, SB2, LA8] -> VM("8") at phases 3/7
//   retires exactly the B DMAs; A loads never drained in-loop.
//   XCD pairing: the two n-halves of an m-panel co-reside on one XCD ->
//   nh's second read is an L2 hit (nh fetched ~once from HBM).

typedef short bf16x8 __attribute__((ext_vector_type(8)));
typedef float f32x4  __attribute__((ext_vector_type(4)));

__device__ __forceinline__ unsigned f2bfbits(float f) {
    unsigned u = __builtin_bit_cast(unsigned, f);
    return (u + 0x7FFFu + ((u >> 16) & 1u)) >> 16;   // round-to-nearest-even
}
__device__ __forceinline__ unsigned pack2(float a, float b) {
    unsigned lo = (unsigned)__builtin_bit_cast(unsigned short, __float2bfloat16(a));
    unsigned hi = (unsigned)__builtin_bit_cast(unsigned short, __float2bfloat16(b));
    return lo | (hi << 16);
}

// ---------------------------------------------------------------------------
// Prep kernel: fold (bid<68) + bias (68-71). Verified r13/r14 (cvt removed).
// ---------------------------------------------------------------------------
#define FS 68

__global__ __launch_bounds__(512) void tt_prep(
    const float* __restrict__ Ag,    // (4,128,64)
    const float* __restrict__ Bg,    // (4,64,64)
    const float* __restrict__ Abg,   // (4,1,64)
    const float* __restrict__ Utg,   // (4,128,64)
    const float* __restrict__ btg,   // (4,1,64)
    const float* __restrict__ Uog,   // (4,64,128)
    const float* __restrict__ bog,   // (4,1,128)
    unsigned short* __restrict__ Bp, // [4][34][8][128][8] bf16
    float* __restrict__ biasOut)     // [512]
{
    __shared__ __align__(16) float L[23552];   // 92 KB
    const int t = threadIdx.x;
    const int bid = blockIdx.x;

    auto mm = [&](float* d, const float* x, const float* y, const float* add) {
        const int r = t >> 3, c0 = (t & 7) << 3;
        float acc[8];
#pragma unroll
        for (int j = 0; j < 8; ++j) acc[j] = 0.f;
        for (int k = 0; k < 64; ++k) {
            const float a = x[r * FS + k];
            const float4 y0 = *(const float4*)(y + k * FS + c0);
            const float4 y1 = *(const float4*)(y + k * FS + c0 + 4);
            acc[0] += a * y0.x; acc[1] += a * y0.y;
            acc[2] += a * y0.z; acc[3] += a * y0.w;
            acc[4] += a * y1.x; acc[5] += a * y1.y;
            acc[6] += a * y1.z; acc[7] += a * y1.w;
        }
        if (add) {
#pragma unroll
            for (int j = 0; j < 8; ++j) acc[j] += add[r * FS + c0 + j];
        }
#pragma unroll
        for (int j = 0; j < 8; ++j) d[r * FS + c0 + j] = acc[j];
    };

    float* buf[4];
    buf[0] = L;
    buf[1] = L + 4352;
    buf[2] = L + 8704;
    buf[3] = L + 13056;
    float* const Pbuf = L + 17408;   // 64x64 dense (stride 64)
    float* const UC   = L + 21504;   // 16x128 staging

    if (bid < 68) {
        int a, p, kbase;
        const float* src;
        if (bid < 64) { a = bid >> 4; const int c = bid & 15; p = 15 - c; kbase = c * 128; src = Ag  + a * 8192; }
        else          { a = bid - 64; p = 16; kbase = 2048;               src = Utg + a * 8192; }
        const float* Bmat = Bg + a * 4096;

        for (int i = t; i < 4096; i += 512) {
            const int row = i >> 6, col = i & 63;
            buf[0][row * FS + col] = Bmat[i];
            buf[2][row * FS + col] = (row == col) ? 1.f : 0.f;
        }
        __syncthreads();
        int bcur = 0, rcur = 2;
        int e = p;
        while (e) {
            if (e & 1) { mm(buf[rcur ^ 1], buf[rcur], buf[bcur], nullptr); rcur ^= 1; __syncthreads(); }
            e >>= 1;
            if (e)     { mm(buf[bcur ^ 1], buf[bcur], buf[bcur], nullptr); bcur ^= 1; __syncthreads(); }
        }

        {
            const int prow = t >> 3, pc0 = (t & 7) << 3;
#pragma unroll
            for (int j = 0; j < 8; ++j)
                Pbuf[prow * 64 + pc0 + j] = buf[rcur][prow * FS + pc0 + j];
        }
        __syncthreads();

        // M1 = src(128x64) @ P, stored stride-65 at L
        float* M1 = L;
        {
            const int i = t >> 2, r0 = (t & 3) << 4;
            float acc[16];
#pragma unroll
            for (int j = 0; j < 16; ++j) acc[j] = 0.f;
            for (int q = 0; q < 64; ++q) {
                const float av = src[i * 64 + q];
                const float4* pr = (const float4*)(Pbuf + q * 64 + r0);
#pragma unroll
                for (int jj = 0; jj < 4; ++jj) {
                    float4 v = pr[jj];
                    acc[4 * jj + 0] += av * v.x;
                    acc[4 * jj + 1] += av * v.y;
                    acc[4 * jj + 2] += av * v.z;
                    acc[4 * jj + 3] += av * v.w;
                }
            }
#pragma unroll
            for (int j = 0; j < 16; ++j) M1[i * 65 + r0 + j] = acc[j];
        }
        __syncthreads();

        // W2 = M1(128x64) @ Uo(64x128)
        const float* UoA = Uog + a * 8192;
        const int i = t >> 2, h0 = (t & 3) << 5;
        float acc2[32];
#pragma unroll
        for (int j = 0; j < 32; ++j) acc2[j] = 0.f;
        for (int ch = 0; ch < 4; ++ch) {
            __syncthreads();
            for (int idx = t; idx < 2048; idx += 512) UC[idx] = UoA[ch * 2048 + idx];
            __syncthreads();
            for (int rr = 0; rr < 16; ++rr) {
                const float m = M1[i * 65 + ch * 16 + rr];
                const float4* ur = (const float4*)(UC + rr * 128 + h0);
#pragma unroll
                for (int jj = 0; jj < 8; ++jj) {
                    float4 v = ur[jj];
                    acc2[4 * jj + 0] += m * v.x;
                    acc2[4 * jj + 1] += m * v.y;
                    acc2[4 * jj + 2] += m * v.z;
                    acc2[4 * jj + 3] += m * v.w;
                }
            }
        }
        // write Bp brick: [nb = n>>7][kt][slot][nloc = n&127][8]
        {
            const int k = kbase + i;
            const int kt = k >> 6, slot = (k >> 3) & 7, widx = k & 7;
#pragma unroll
            for (int j = 0; j < 32; ++j) {
                const int n = a * 128 + h0 + j;
                Bp[((size_t)(((n >> 7) * 34 + kt) * 8 + slot)) * 1024 + (n & 127) * 8 + widx] =
                    (unsigned short)f2bfbits(acc2[j]);
            }
        }
    } else {
        // bias: S16 = sum_{p<16} B^p, B16 = B^16
        const int a = bid - 68;
        const float* Bmat = Bg + a * 4096;
        for (int i = t; i < 4096; i += 512) {
            const int row = i >> 6, col = i & 63;
            buf[0][row * FS + col] = Bmat[i];
            buf[2][row * FS + col] = (row == col) ? 1.f : 0.f;
        }
        __syncthreads();
        int bcur = 0, scur = 2;
        for (int rnd = 0; rnd < 4; ++rnd) {
            mm(buf[scur ^ 1], buf[bcur], buf[scur], buf[scur]);
            mm(buf[bcur ^ 1], buf[bcur], buf[bcur], nullptr);
            __syncthreads();
            scur ^= 1; bcur ^= 1;
        }
        float* vv = Pbuf;
        if (t < 64) {
            float acc = 0.f;
            const float* S16 = buf[scur];
            const float* B16 = buf[bcur];
            for (int q = 0; q < 64; ++q)
                acc += Abg[a * 64 + q] * S16[q * FS + t]
                     + btg[a * 64 + q] * B16[q * FS + t];
            vv[t] = acc;
        }
        __syncthreads();
        if (t < 128) {
            float accb = bog[a * 128 + t];
            const float* UoA = Uog + a * 8192;
            for (int r = 0; r < 64; ++r) accb += vv[r] * UoA[r * 128 + t];
            biasOut[a * 128 + t] = accb;
        }
    }
}
#undef FS

// ---------------------------------------------------------------------------
// Fused 8-phase GEMM: 256 blocks x 512 thr. Tile 256x256, BK=64 (34 tiles,
// 17 pairs). La = A bf16 [d][rowhalf(2)][slot8][row128][8] (2x32KB),
// Lb = B bricks (2x32KB). A staged f32->regs->cvt->ds_write in-loop.
// ---------------------------------------------------------------------------
__global__ __launch_bounds__(512) void tt_gemm(
    const float* __restrict__ nh,           // (32768,16,128)
    const float* __restrict__ te,           // (32768,128)
    const unsigned short* __restrict__ Bp,  // [4][34][8][128][8]
    const float* __restrict__ bias,         // [512]
    float* __restrict__ out)                // (32768,512)
{
    __shared__ __align__(16) char Lds[131072];  // La 2x32K @0, Lb 2x32K @64K

    const int t = threadIdx.x;
    const int lane = t & 63, w = t >> 6;
    const int lt = (blockIdx.x & 7) * 32 + (blockIdx.x >> 3);   // 256 = 8*32
    const int m0 = (lt >> 1) * 256;
    const int nblk = lt & 1;
    const int wr = w >> 2, wc = w & 3;
    const int lx = lane & 15, lg = lane >> 4;

    // A staging: thread -> row r (0..255), k-half h2 (32 f32)
    const int r = t >> 1, h2 = t & 1;
    const float* nhp = nh + (size_t)(m0 + r) * 2048 + h2 * 32;
    const float* tep = te + (size_t)(m0 + r) * 128  + h2 * 32;
    // A ds_write base (byte, within La): + d*32768 + (4*h2+j)*2048
    const int awb = (r >> 7) * 16384 + (r & 127) * 16;

    // B DMA source base (per-lane)
    const char* const bpb = (const char*)Bp + (size_t)(nblk * 2) * 34 * 16384
                            + w * 1024 + lane * 16;
    char* const La = Lds;
    char* const Lb = Lds + 65536;

    // frag read offsets
    const int aro = wr * 16384 + lx * 16;   // + d*32768 + (kk*4+lg)*2048 + fm*256
    int bco[4];
#pragma unroll
    for (int fn = 0; fn < 4; ++fn) {
        const int col = wc * 64 + fn * 16 + lx;
        bco[fn] = (col >> 7) * 16384 + (col & 127) * 16;
    }

    f32x4 acc[8][4] = {};
    bf16x8 aF[4][2], bF0[2][2], bF1[2][2];
    float4 va0[8], va1[8];     // A f32 staging (named, distance ~4-6 phases)

#define BAR()  __builtin_amdgcn_s_barrier()
#define LGKM0() do { asm volatile("s_waitcnt lgkmcnt(0)" ::: "memory"); \
                     __builtin_amdgcn_sched_barrier(0); } while (0)
#define PRIO(x) __builtin_amdgcn_s_setprio(x)
#define VM(NSTR) asm volatile("s_waitcnt vmcnt(" NSTR ")" ::: "memory")

#define STAGEB(d_, h_, kt_) do {                                               \
    const char* _s = bpb + (size_t)((h_) * 34 + (kt_)) * 16384;                \
    char* _d = Lb + (d_) * 32768 + (h_) * 16384 + w * 1024;                    \
    __builtin_amdgcn_global_load_lds(                                          \
        (const __attribute__((address_space(1))) unsigned int*)_s,             \
        (__attribute__((address_space(3))) unsigned int*)_d, 16, 0, 0);        \
    __builtin_amdgcn_global_load_lds(                                          \
        (const __attribute__((address_space(1))) unsigned int*)(_s + 8192),    \
        (__attribute__((address_space(3))) unsigned int*)(_d + 8192), 16, 0, 0); \
} while (0)

#define LOADA(dst, kt_) do {                                                   \
    const float* _p = ((kt_) < 32) ? (nhp + (kt_) * 64) : (tep + ((kt_) - 32) * 64); \
    _Pragma("unroll")                                                          \
    for (int _j = 0; _j < 8; ++_j) dst[_j] = *(const float4*)(_p + 4 * _j);    \
} while (0)

// write 2 of 4 k-slot uint4s (j0, j0+1) of this thread's row into La[d_]
#define WRITEA_J(src, d_, j0) do {                                             \
    _Pragma("unroll")                                                          \
    for (int _j = (j0); _j < (j0) + 2; ++_j) {                                 \
        uint4 _w;                                                              \
        _w.x = pack2(src[2 * _j].x,     src[2 * _j].y);                        \
        _w.y = pack2(src[2 * _j].z,     src[2 * _j].w);                        \
        _w.z = pack2(src[2 * _j + 1].x, src[2 * _j + 1].y);                    \
        _w.w = pack2(src[2 * _j + 1].z, src[2 * _j + 1].w);                    \
        *(uint4*)(La + (d_) * 32768 + awb + (4 * h2 + _j) * 2048) = _w;        \
    }                                                                          \
} while (0)

#define RDA(d_, fmb) do {                                                      \
    _Pragma("unroll")                                                          \
    for (int _f = 0; _f < 4; ++_f)                                             \
        _Pragma("unroll")                                                      \
        for (int _k = 0; _k < 2; ++_k)                                         \
            aF[_f][_k] = *(const bf16x8*)(La + (d_) * 32768 +                  \
                (_k * 4 + lg) * 2048 + aro + ((fmb) + _f) * 256);              \
} while (0)

#define RDB(dst, d_, fnb) do {                                                 \
    _Pragma("unroll")                                                          \
    for (int _f = 0; _f < 2; ++_f)                                             \
        _Pragma("unroll")                                                      \
        for (int _k = 0; _k < 2; ++_k)                                         \
            dst[_f][_k] = *(const bf16x8*)(Lb + (d_) * 32768 +                 \
                (_k * 4 + lg) * 2048 + bco[(fnb) + _f]);                       \
} while (0)

#define QMFMA(fmb, fnb, bf) do {                                               \
    _Pragma("unroll")                                                          \
    for (int _f = 0; _f < 4; ++_f)                                             \
        _Pragma("unroll")                                                      \
        for (int _n = 0; _n < 2; ++_n)                                         \
            _Pragma("unroll")                                                  \
            for (int _k = 0; _k < 2; ++_k)                                     \
                acc[(fmb) + _f][(fnb) + _n] =                                  \
                    __builtin_amdgcn_mfma_f32_16x16x32_bf16(                   \
                        aF[_f][_k], bf[_n][_k],                                \
                        acc[(fmb) + _f][(fnb) + _n], 0, 0, 0);                 \
} while (0)

    // ---- prologue: A tile0 -> La0 (via transient regs); va1 <- tile1;
    //      B tile0 -> Lb0 via DMA; drain; barrier. ----
    {
        float4 tmp[8];
        LOADA(tmp, 0);
        WRITEA_J(tmp, 0, 0);
        WRITEA_J(tmp, 0, 2);
    }
    LOADA(va1, 1);
    STAGEB(0, 0, 0);
    STAGEB(0, 1, 0);
    asm volatile("s_waitcnt vmcnt(0) lgkmcnt(0)" ::: "memory");
    BAR();

#pragma unroll 1
    for (int i = 0; i < 17; ++i) {
        const int t1 = 2 * i + 1, ta = 2 * i + 2;
        const bool g = ta < 34;

        // ========== tile t0 = 2i (bufs 0) ==========
        // ph0: Q00
        STAGEB(1, 0, t1);
        RDA(0, 0);
        RDB(bF0, 0, 0);
        BAR(); LGKM0(); PRIO(1);
        QMFMA(0, 0, bF0);
        PRIO(0); BAR();

        // ph1: Q01
        STAGEB(1, 1, t1);
        RDB(bF1, 0, 2);
        BAR(); LGKM0(); PRIO(1);
        QMFMA(0, 2, bF1);
        PRIO(0); BAR();

        // ph2: Q10 (+ A write half of t1; issue A loads for ta)
        WRITEA_J(va1, 1, 0);          // compiler-counted wait on va1's loads
        if (g) LOADA(va0, ta);
        RDA(0, 4);
        BAR(); LGKM0(); PRIO(1);
        QMFMA(4, 0, bF0);
        PRIO(0); BAR();

        // ph3: Q11 (+ A write half 2; counted VM retires B(t1) DMAs only)
        WRITEA_J(va1, 1, 2);
        BAR(); PRIO(1);
        QMFMA(4, 2, bF1);
        PRIO(0);
        LGKM0();
        if (g) VM("8"); else VM("0");
        BAR();

        // ========== tile t1 = 2i+1 (bufs 1) ==========
        // ph4: Q00
        if (g) STAGEB(0, 0, ta);
        RDA(1, 0);
        RDB(bF0, 1, 0);
        BAR(); LGKM0(); PRIO(1);
        QMFMA(0, 0, bF0);
        PRIO(0); BAR();

        // ph5: Q01
        if (g) STAGEB(0, 1, ta);
        RDB(bF1, 1, 2);
        BAR(); LGKM0(); PRIO(1);
        QMFMA(0, 2, bF1);
        PRIO(0); BAR();

        // ph6: Q10 (+ A write half of ta; issue A loads for ta+1)
        if (g) { WRITEA_J(va0, 0, 0); LOADA(va1, ta + 1); }
        RDA(1, 4);
        BAR(); LGKM0(); PRIO(1);
        QMFMA(4, 0, bF0);
        PRIO(0); BAR();

        // ph7: Q11 (+ A write half 2; counted VM retires B(ta) DMAs only)
        if (g) WRITEA_J(va0, 0, 2);
        BAR(); PRIO(1);
        QMFMA(4, 2, bF1);
        PRIO(0);
        if (g) { LGKM0(); VM("8"); BAR(); }
    }

#undef QMFMA
#undef RDB
#undef RDA
#undef WRITEA_J
#undef LOADA
#undef STAGEB
#undef VM
#undef PRIO
#undef LGKM0
#undef BAR

    // epilogue: C/D layout col = lane&15, row = (lane>>4)*4 + reg  [m89]
    const int orow = m0 + wr * 128 + lg * 4;
    const int ocol = nblk * 256 + wc * 64 + lx;
    float bv[4];
#pragma unroll
    for (int fn = 0; fn < 4; ++fn) bv[fn] = bias[ocol + fn * 16];
#pragma unroll
    for (int fm = 0; fm < 8; ++fm)
#pragma unroll
        for (int fn = 0; fn < 4; ++fn)
#pragma unroll
            for (int j = 0; j < 4; ++j)
                out[(size_t)(orow + fm * 16 + j) * 512 + ocol + fn * 16] =
                    acc[fm][fn][j] + bv[fn];
}

// ---------------------------------------------------------------------------
extern "C" void kernel_launch(void* const* d_in, const int* in_sizes, int n_in,
                              void* d_out, int out_size, void* d_ws, size_t ws_size,
                              hipStream_t stream) {
    const float* nh  = (const float*)d_in[0];
    const float* te  = (const float*)d_in[1];
    const float* Ag  = (const float*)d_in[2];
    const float* Bg  = (const float*)d_in[3];
    const float* Abg = (const float*)d_in[4];
    const float* Utg = (const float*)d_in[5];
    const float* btg = (const float*)d_in[6];
    const float* Uog = (const float*)d_in[7];
    const float* bog = (const float*)d_in[8];

    unsigned short* Bp = (unsigned short*)d_ws;               // 2,228,224 B
    float* bias = (float*)((char*)d_ws + 2228224);            // 2,048 B
    float* out = (float*)d_out;

    hipLaunchKernelGGL(tt_prep, dim3(72), dim3(512), 0, stream,
                       Ag, Bg, Abg, Utg, btg, Uog, bog, Bp, bias);
    hipLaunchKernelGGL(tt_gemm, dim3(256), dim3(512), 0, stream,
                       nh, te, Bp, bias, out);
}

// Round 16
// 204.091 us; speedup vs baseline: 2.0397x; 2.0397x over previous
//
#include <hip/hip_runtime.h>
#include <hip/hip_bf16.h>

// TensorTrainLMN: out[b, a*128+h] = X[b,:] @ W[:, a*128+h] + bias
//   X[b] = [nh[b,0,:128], ..., nh[b,15,:128], te[b,:128]]   (K = 2176)
//
// tt_prep (72 blocks x 512): fold W -> Bp bricks [nb4][kt34][slot8][128][8]
//   bf16 + bias. (verified r13-r15)
// tt_gemm (FUSED, zero staging VGPRs): 256x256 tile, BK=32 (68 K-tiles),
//   512 thr (8 waves 2x4, wave 128x64). A staged as F32 via global_load_lds
//   (source-side XOR swizzle k4^=row&7; f32->bf16 cvt at READ side). B via
//   DMA of pre-packed bricks. 3-slot LDS ring (A 3x32K + B 3x16K = 144KB),
//   tile t stages t+2 (distance 2 tiles = 4 phases), VM("6") at tile end
//   retires exactly t+1's 6 DMAs (never drains fresh loads). 2 phases/tile
//   {fm0-3, fm4-7}, only bF[4] live across the intra-tile barrier.

typedef short bf16x8 __attribute__((ext_vector_type(8)));
typedef float f32x4  __attribute__((ext_vector_type(4)));

__device__ __forceinline__ unsigned f2bfbits(float f) {
    unsigned u = __builtin_bit_cast(unsigned, f);
    return (u + 0x7FFFu + ((u >> 16) & 1u)) >> 16;   // round-to-nearest-even
}
__device__ __forceinline__ unsigned pack2(float a, float b) {
    unsigned lo = (unsigned)__builtin_bit_cast(unsigned short, __float2bfloat16(a));
    unsigned hi = (unsigned)__builtin_bit_cast(unsigned short, __float2bfloat16(b));
    return lo | (hi << 16);
}

// ---------------------------------------------------------------------------
// Prep kernel: fold (bid<68) + bias (68-71). Verified r13-r15.
// ---------------------------------------------------------------------------
#define FS 68

__global__ __launch_bounds__(512) void tt_prep(
    const float* __restrict__ Ag,    // (4,128,64)
    const float* __restrict__ Bg,    // (4,64,64)
    const float* __restrict__ Abg,   // (4,1,64)
    const float* __restrict__ Utg,   // (4,128,64)
    const float* __restrict__ btg,   // (4,1,64)
    const float* __restrict__ Uog,   // (4,64,128)
    const float* __restrict__ bog,   // (4,1,128)
    unsigned short* __restrict__ Bp, // [4][34][8][128][8] bf16
    float* __restrict__ biasOut)     // [512]
{
    __shared__ __align__(16) float L[23552];   // 92 KB
    const int t = threadIdx.x;
    const int bid = blockIdx.x;

    auto mm = [&](float* d, const float* x, const float* y, const float* add) {
        const int r = t >> 3, c0 = (t & 7) << 3;
        float acc[8];
#pragma unroll
        for (int j = 0; j < 8; ++j) acc[j] = 0.f;
        for (int k = 0; k < 64; ++k) {
            const float a = x[r * FS + k];
            const float4 y0 = *(const float4*)(y + k * FS + c0);
            const float4 y1 = *(const float4*)(y + k * FS + c0 + 4);
            acc[0] += a * y0.x; acc[1] += a * y0.y;
            acc[2] += a * y0.z; acc[3] += a * y0.w;
            acc[4] += a * y1.x; acc[5] += a * y1.y;
            acc[6] += a * y1.z; acc[7] += a * y1.w;
        }
        if (add) {
#pragma unroll
            for (int j = 0; j < 8; ++j) acc[j] += add[r * FS + c0 + j];
        }
#pragma unroll
        for (int j = 0; j < 8; ++j) d[r * FS + c0 + j] = acc[j];
    };

    float* buf[4];
    buf[0] = L;
    buf[1] = L + 4352;
    buf[2] = L + 8704;
    buf[3] = L + 13056;
    float* const Pbuf = L + 17408;   // 64x64 dense (stride 64)
    float* const UC   = L + 21504;   // 16x128 staging

    if (bid < 68) {
        int a, p, kbase;
        const float* src;
        if (bid < 64) { a = bid >> 4; const int c = bid & 15; p = 15 - c; kbase = c * 128; src = Ag  + a * 8192; }
        else          { a = bid - 64; p = 16; kbase = 2048;               src = Utg + a * 8192; }
        const float* Bmat = Bg + a * 4096;

        for (int i = t; i < 4096; i += 512) {
            const int row = i >> 6, col = i & 63;
            buf[0][row * FS + col] = Bmat[i];
            buf[2][row * FS + col] = (row == col) ? 1.f : 0.f;
        }
        __syncthreads();
        int bcur = 0, rcur = 2;
        int e = p;
        while (e) {
            if (e & 1) { mm(buf[rcur ^ 1], buf[rcur], buf[bcur], nullptr); rcur ^= 1; __syncthreads(); }
            e >>= 1;
            if (e)     { mm(buf[bcur ^ 1], buf[bcur], buf[bcur], nullptr); bcur ^= 1; __syncthreads(); }
        }

        {
            const int prow = t >> 3, pc0 = (t & 7) << 3;
#pragma unroll
            for (int j = 0; j < 8; ++j)
                Pbuf[prow * 64 + pc0 + j] = buf[rcur][prow * FS + pc0 + j];
        }
        __syncthreads();

        // M1 = src(128x64) @ P, stored stride-65 at L
        float* M1 = L;
        {
            const int i = t >> 2, r0 = (t & 3) << 4;
            float acc[16];
#pragma unroll
            for (int j = 0; j < 16; ++j) acc[j] = 0.f;
            for (int q = 0; q < 64; ++q) {
                const float av = src[i * 64 + q];
                const float4* pr = (const float4*)(Pbuf + q * 64 + r0);
#pragma unroll
                for (int jj = 0; jj < 4; ++jj) {
                    float4 v = pr[jj];
                    acc[4 * jj + 0] += av * v.x;
                    acc[4 * jj + 1] += av * v.y;
                    acc[4 * jj + 2] += av * v.z;
                    acc[4 * jj + 3] += av * v.w;
                }
            }
#pragma unroll
            for (int j = 0; j < 16; ++j) M1[i * 65 + r0 + j] = acc[j];
        }
        __syncthreads();

        // W2 = M1(128x64) @ Uo(64x128)
        const float* UoA = Uog + a * 8192;
        const int i = t >> 2, h0 = (t & 3) << 5;
        float acc2[32];
#pragma unroll
        for (int j = 0; j < 32; ++j) acc2[j] = 0.f;
        for (int ch = 0; ch < 4; ++ch) {
            __syncthreads();
            for (int idx = t; idx < 2048; idx += 512) UC[idx] = UoA[ch * 2048 + idx];
            __syncthreads();
            for (int rr = 0; rr < 16; ++rr) {
                const float m = M1[i * 65 + ch * 16 + rr];
                const float4* ur = (const float4*)(UC + rr * 128 + h0);
#pragma unroll
                for (int jj = 0; jj < 8; ++jj) {
                    float4 v = ur[jj];
                    acc2[4 * jj + 0] += m * v.x;
                    acc2[4 * jj + 1] += m * v.y;
                    acc2[4 * jj + 2] += m * v.z;
                    acc2[4 * jj + 3] += m * v.w;
                }
            }
        }
        // write Bp brick: [nb = n>>7][kt][slot][nloc = n&127][8]
        {
            const int k = kbase + i;
            const int kt = k >> 6, slot = (k >> 3) & 7, widx = k & 7;
#pragma unroll
            for (int j = 0; j < 32; ++j) {
                const int n = a * 128 + h0 + j;
                Bp[((size_t)(((n >> 7) * 34 + kt) * 8 + slot)) * 1024 + (n & 127) * 8 + widx] =
                    (unsigned short)f2bfbits(acc2[j]);
            }
        }
    } else {
        // bias: S16 = sum_{p<16} B^p, B16 = B^16
        const int a = bid - 68;
        const float* Bmat = Bg + a * 4096;
        for (int i = t; i < 4096; i += 512) {
            const int row = i >> 6, col = i & 63;
            buf[0][row * FS + col] = Bmat[i];
            buf[2][row * FS + col] = (row == col) ? 1.f : 0.f;
        }
        __syncthreads();
        int bcur = 0, scur = 2;
        for (int rnd = 0; rnd < 4; ++rnd) {
            mm(buf[scur ^ 1], buf[bcur], buf[scur], buf[scur]);
            mm(buf[bcur ^ 1], buf[bcur], buf[bcur], nullptr);
            __syncthreads();
            scur ^= 1; bcur ^= 1;
        }
        float* vv = Pbuf;
        if (t < 64) {
            float acc = 0.f;
            const float* S16 = buf[scur];
            const float* B16 = buf[bcur];
            for (int q = 0; q < 64; ++q)
                acc += Abg[a * 64 + q] * S16[q * FS + t]
                     + btg[a * 64 + q] * B16[q * FS + t];
            vv[t] = acc;
        }
        __syncthreads();
        if (t < 128) {
            float accb = bog[a * 128 + t];
            const float* UoA = Uog + a * 8192;
            for (int r = 0; r < 64; ++r) accb += vv[r] * UoA[r * 128 + t];
            biasOut[a * 128 + t] = accb;
        }
    }
}
#undef FS

// ---------------------------------------------------------------------------
// Fused GEMM: 256 blocks x 512 thr. Tile 256x256, BK=32, 68 K-tiles.
// LDS: La = 3 x 32KB f32 A-slots @0 ([line4][row64][k4slot8 xor-swz][16B]);
//      Lb = 3 x 16KB B-slots @98304 ([h2][s2(4)][nloc128][16B]).
// ---------------------------------------------------------------------------
__global__ __launch_bounds__(512) void tt_gemm(
    const float* __restrict__ nh,           // (32768,16,128)
    const float* __restrict__ te,           // (32768,128)
    const unsigned short* __restrict__ Bp,  // [4][34][8][128][8]
    const float* __restrict__ bias,         // [512]
    float* __restrict__ out)                // (32768,512)
{
    __shared__ __align__(16) char Lds[147456];

    const int t = threadIdx.x;
    const int lane = t & 63, w = t >> 6;
    // chunked XCD map: both n-halves of an m-panel co-reside on one XCD
    const int lt = (blockIdx.x & 7) * 32 + (blockIdx.x >> 3);   // 256 = 8*32
    const int m0 = (lt >> 1) * 256;
    const int nblk = lt & 1;
    const int wr = w >> 2, wc = w & 3;
    const int lx = lane & 15, lg = lane >> 4;

    char* const La = Lds;              // + slot*32768
    char* const Lb = Lds + 98304;      // + slot*16384

    // ---- A DMA geometry: flat thread id -> (row_local 0..63, k4 0..7),
    //      source k4 pre-swizzled by row (rule 21; read applies same XOR).
    const int flat = t;
    const int rowA = flat >> 3, k4 = flat & 7;
    const int k4s = k4 ^ (rowA & 7);
    const char* const anh = (const char*)nh + (size_t)(m0 + rowA) * 8192 + k4s * 16;
    const char* const ate = (const char*)te + (size_t)(m0 + rowA) * 512  + k4s * 16;
    char* const adst = La + flat * 16;          // + slot*32768 + j*8192

    // ---- B DMA geometry (r14 path, BK=32 = half a BK-64 brick)
    const char* const bpb = (const char*)Bp + (size_t)(nblk * 2) * 34 * 16384
                            + w * 1024 + lane * 16;
    char* const bdst = Lb + w * 1024 + lane * 16;   // + slot*16384 + h*8192

    // ---- A frag read offsets (within an A slot): lo/hi 16B per fm
    int aLo[8], aHi[8];
#pragma unroll
    for (int fm = 0; fm < 8; ++fm) {
        const int row = wr * 128 + fm * 16 + lx;
        const int base = (row >> 6) * 8192 + (row & 63) * 128;
        const int s0 = (2 * lg) ^ (row & 7);
        aLo[fm] = base + s0 * 16;
        aHi[fm] = base + (s0 ^ 1) * 16;
    }
    // ---- B frag read offsets (within a B slot): + lg*2048
    int bOff[4];
#pragma unroll
    for (int fn = 0; fn < 4; ++fn) {
        const int col = wc * 64 + fn * 16 + lx;
        bOff[fn] = (col >> 7) * 8192 + (col & 127) * 16 + lg * 2048;
    }

    f32x4 acc[8][4] = {};
    bf16x8 aF[4], bF[4];

#define BAR()  __builtin_amdgcn_s_barrier()
#define LGKM0() do { asm volatile("s_waitcnt lgkmcnt(0)" ::: "memory"); \
                     __builtin_amdgcn_sched_barrier(0); } while (0)
#define PRIO(x) __builtin_amdgcn_s_setprio(x)
#define VM(NSTR) asm volatile("s_waitcnt vmcnt(" NSTR ")" ::: "memory")

#define GLD(src_, dst_) __builtin_amdgcn_global_load_lds(                      \
    (const __attribute__((address_space(1))) unsigned int*)(src_),             \
    (__attribute__((address_space(3))) unsigned int*)(dst_), 16, 0, 0)

// stage A f32 tile t_ into slot sl_: 4 instr-lines of 8KB
#define STAGEA(sl_, t_) do {                                                   \
    char* _d = adst + (sl_) * 32768;                                           \
    if ((t_) < 64) {                                                           \
        const char* _s = anh + ((t_) >> 2) * 512 + ((t_) & 3) * 128;           \
        _Pragma("unroll")                                                      \
        for (int _j = 0; _j < 4; ++_j) GLD(_s + _j * 524288, _d + _j * 8192);  \
    } else {                                                                   \
        const char* _s = ate + ((t_) - 64) * 128;                              \
        _Pragma("unroll")                                                      \
        for (int _j = 0; _j < 4; ++_j) GLD(_s + _j * 32768, _d + _j * 8192);   \
    }                                                                          \
} while (0)

// stage B tile t_ into slot sl_: 2 instr-lines (nb halves)
#define STAGEB(sl_, t_) do {                                                   \
    const char* _s = bpb + (size_t)((t_) >> 1) * 16384 + ((t_) & 1) * 8192;    \
    char* _d = bdst + (sl_) * 16384;                                           \
    GLD(_s, _d);                                                               \
    GLD(_s + (size_t)34 * 16384, _d + 8192);                                   \
} while (0)

// read + cvt 4 A frags (fm = fmb..fmb+3) from slot sl_
#define RDA(sl_, fmb) do {                                                     \
    _Pragma("unroll")                                                          \
    for (int _f = 0; _f < 4; ++_f) {                                           \
        const char* _b = La + (sl_) * 32768;                                   \
        f32x4 _lo = *(const f32x4*)(_b + aLo[(fmb) + _f]);                     \
        f32x4 _hi = *(const f32x4*)(_b + aHi[(fmb) + _f]);                     \
        uint4 _u;                                                              \
        _u.x = pack2(_lo[0], _lo[1]);  _u.y = pack2(_lo[2], _lo[3]);           \
        _u.z = pack2(_hi[0], _hi[1]);  _u.w = pack2(_hi[2], _hi[3]);           \
        aF[_f] = __builtin_bit_cast(bf16x8, _u);                               \
    }                                                                          \
} while (0)

#define RDB(sl_) do {                                                          \
    _Pragma("unroll")                                                          \
    for (int _n = 0; _n < 4; ++_n)                                             \
        bF[_n] = *(const bf16x8*)(Lb + (sl_) * 16384 + bOff[_n]);              \
} while (0)

#define MM16(fmb) do {                                                         \
    _Pragma("unroll")                                                          \
    for (int _f = 0; _f < 4; ++_f)                                             \
        _Pragma("unroll")                                                      \
        for (int _n = 0; _n < 4; ++_n)                                         \
            acc[(fmb) + _f][_n] = __builtin_amdgcn_mfma_f32_16x16x32_bf16(     \
                aF[_f], bF[_n], acc[(fmb) + _f][_n], 0, 0, 0);                 \
} while (0)

    // ---- prologue: stage tiles 0 (slot 0) and 1 (slot 1); drain; barrier.
    STAGEA(0, 0); STAGEB(0, 0);
    STAGEA(1, 1); STAGEB(1, 1);
    asm volatile("s_waitcnt vmcnt(0)" ::: "memory");
    BAR();

    int sl = 0;
#pragma unroll 1
    for (int kt = 0; kt < 68; ++kt) {
        const int t2 = kt + 2;
        const bool g = t2 < 68;
        const int s2 = (sl >= 1) ? sl - 1 : sl + 2;   // (sl+2)%3

        // ---- phase 0: fm0-3 x fn0-3 ----
        if (g) STAGEA(s2, t2);
        RDA(sl, 0);
        RDB(sl);
        BAR(); LGKM0(); PRIO(1);
        MM16(0);
        PRIO(0); BAR();

        // ---- phase 1: fm4-7 x fn0-3 ----
        if (g) STAGEB(s2, t2);
        RDA(sl, 4);
        BAR(); LGKM0(); PRIO(1);
        MM16(4);
        PRIO(0);
        // counted: retire tile kt+1's 6 DMAs (issued last tile); keep t2's 6
        if (g) VM("6");
        else if (kt == 66) VM("0");
        BAR();

        sl = (sl == 2) ? 0 : sl + 1;
    }

#undef MM16
#undef RDB
#undef RDA
#undef STAGEB
#undef STAGEA
#undef GLD
#undef VM
#undef PRIO
#undef LGKM0
#undef BAR

    // epilogue: C/D layout col = lane&15, row = (lane>>4)*4 + reg  [m89]
    const int orow = m0 + wr * 128 + lg * 4;
    const int ocol = nblk * 256 + wc * 64 + lx;
    float bv[4];
#pragma unroll
    for (int fn = 0; fn < 4; ++fn) bv[fn] = bias[ocol + fn * 16];
#pragma unroll
    for (int fm = 0; fm < 8; ++fm)
#pragma unroll
        for (int fn = 0; fn < 4; ++fn)
#pragma unroll
            for (int j = 0; j < 4; ++j)
                out[(size_t)(orow + fm * 16 + j) * 512 + ocol + fn * 16] =
                    acc[fm][fn][j] + bv[fn];
}

// ---------------------------------------------------------------------------
extern "C" void kernel_launch(void* const* d_in, const int* in_sizes, int n_in,
                              void* d_out, int out_size, void* d_ws, size_t ws_size,
                              hipStream_t stream) {
    const float* nh  = (const float*)d_in[0];
    const float* te  = (const float*)d_in[1];
    const float* Ag  = (const float*)d_in[2];
    const float* Bg  = (const float*)d_in[3];
    const float* Abg = (const float*)d_in[4];
    const float* Utg = (const float*)d_in[5];
    const float* btg = (const float*)d_in[6];
    const float* Uog = (const float*)d_in[7];
    const float* bog = (const float*)d_in[8];

    unsigned short* Bp = (unsigned short*)d_ws;               // 2,228,224 B
    float* bias = (float*)((char*)d_ws + 2228224);            // 2,048 B
    float* out = (float*)d_out;

    hipLaunchKernelGGL(tt_prep, dim3(72), dim3(512), 0, stream,
                       Ag, Bg, Abg, Utg, btg, Uog, bog, Bp, bias);
    hipLaunchKernelGGL(tt_gemm, dim3(256), dim3(512), 0, stream,
                       nh, te, Bp, bias, out);
}